// Round 1
// baseline (900.669 us; speedup 1.0000x reference)
//
#include <hip/hip_runtime.h>
#include <math.h>

#define B_ 128
#define S_ 256
#define H_ 1024
#define E_ 512
#define V_ 32000

// ---------------------------------------------------------------- embed gather
__global__ __launch_bounds__(256) void embed_kernel(const int* __restrict__ x,
                                                    const float* __restrict__ emb,
                                                    float* __restrict__ x_emb)
{
    int idx = blockIdx.x * 256 + threadIdx.x;     // B*E
    int b = idx >> 9;                              // E_=512
    int e = idx & 511;
    x_emb[idx] = emb[(size_t)x[b] * E_ + e];
}

// ---------------------------------------------------------------- C[b,n] = bias[n]
__global__ __launch_bounds__(256) void bias_init(float* __restrict__ C,
                                                 const float* __restrict__ bias, int N)
{
    int idx = blockIdx.x * 256 + threadIdx.x;
    int n = idx % N;
    C[idx] = bias[n];
}

// ---------------------------------------------------------------- generic GEMM core
// C[m,n] (+)= sum_k A[m,k] * W[n,k]    M=128 fixed, 256 threads, TILE_K=16
template<int TILE_N, int MICRO_N, bool ATOMIC>
__device__ __forceinline__ void gemm_core(const float* __restrict__ A,
                                          const float* __restrict__ W,
                                          const float* __restrict__ bias,
                                          float* __restrict__ C,
                                          int N, int K, int kbeg, int kend,
                                          float (*As)[132], float (*Ws)[TILE_N + 4])
{
    constexpr int NT_N   = TILE_N / MICRO_N;   // threads along n
    constexpr int NT_M   = 256 / NT_N;         // threads along m
    constexpr int MICRO_M = 128 / NT_M;        // rows per thread
    const int tid = threadIdx.x;
    const int n0  = blockIdx.x * TILE_N;
    const int tn  = (tid % NT_N) * MICRO_N;
    const int tm  = (tid / NT_N) * MICRO_M;

    float acc[MICRO_M][MICRO_N] = {};

    for (int k0 = kbeg; k0 < kend; k0 += 16) {
        // A tile: 128x16 floats = 512 float4, 2 per thread
        #pragma unroll
        for (int r = 0; r < 2; r++) {
            int v  = tid + 256 * r;
            int m  = v >> 2;
            int kk = (v & 3) << 2;
            float4 a4 = *(const float4*)(A + (size_t)m * K + k0 + kk);
            As[kk + 0][m] = a4.x; As[kk + 1][m] = a4.y;
            As[kk + 2][m] = a4.z; As[kk + 3][m] = a4.w;
        }
        // W tile: TILE_N x16 floats = TILE_N*4 float4
        for (int v = tid; v < TILE_N * 4; v += 256) {
            int n  = v >> 2;
            int kk = (v & 3) << 2;
            float4 w4 = *(const float4*)(W + (size_t)(n0 + n) * K + k0 + kk);
            Ws[kk + 0][n] = w4.x; Ws[kk + 1][n] = w4.y;
            Ws[kk + 2][n] = w4.z; Ws[kk + 3][n] = w4.w;
        }
        __syncthreads();
        #pragma unroll
        for (int kk = 0; kk < 16; kk++) {
            float a[MICRO_M], w[MICRO_N];
            #pragma unroll
            for (int i = 0; i < MICRO_M; i++) a[i] = As[kk][tm + i];
            #pragma unroll
            for (int j = 0; j < MICRO_N; j++) w[j] = Ws[kk][tn + j];
            #pragma unroll
            for (int i = 0; i < MICRO_M; i++)
                #pragma unroll
                for (int j = 0; j < MICRO_N; j++)
                    acc[i][j] = fmaf(a[i], w[j], acc[i][j]);
        }
        __syncthreads();
    }

    #pragma unroll
    for (int i = 0; i < MICRO_M; i++) {
        #pragma unroll
        for (int j = 0; j < MICRO_N; j++) {
            size_t off = (size_t)(tm + i) * N + n0 + tn + j;
            if (ATOMIC) atomicAdd(C + off, acc[i][j]);
            else        C[off] = acc[i][j] + bias[n0 + tn + j];
        }
    }
}

// big GEMM (z): TILE_N=64, micro 8x4, no split-K, bias fused
__global__ __launch_bounds__(256) void gemm_z(const float* __restrict__ A,
                                              const float* __restrict__ W,
                                              const float* __restrict__ bias,
                                              float* __restrict__ C, int N, int K)
{
    __shared__ float As[16][132];
    __shared__ float Ws[16][68];
    gemm_core<64, 4, false>(A, W, bias, C, N, K, 0, K, As, Ws);
}

// dual mid GEMM: two problems selected by blockIdx.z, split-K via blockIdx.y,
// atomicAdd into bias-pre-initialized C
__global__ __launch_bounds__(256) void gemm_dual(const float* A0, const float* W0, float* C0, int K0, int kc0,
                                                 const float* A1, const float* W1, float* C1, int K1, int kc1,
                                                 int N)
{
    __shared__ float As[16][132];
    __shared__ float Ws[16][36];
    if (blockIdx.z == 0)
        gemm_core<32, 2, true>(A0, W0, nullptr, C0, N, K0,
                               blockIdx.y * kc0, blockIdx.y * kc0 + kc0, As, Ws);
    else
        gemm_core<32, 2, true>(A1, W1, nullptr, C1, N, K1,
                               blockIdx.y * kc1, blockIdx.y * kc1 + kc1, As, Ws);
}

// ---------------------------------------------------------------- pt = (len-1)*sigmoid(w_proj . tanh(dwpos))
__global__ __launch_bounds__(256) void pt_kernel(const int* __restrict__ masks,
                                                 const float* __restrict__ dwpos,
                                                 const float* __restrict__ w_proj,
                                                 float* __restrict__ pt)
{
    __shared__ int   smin_s[4];
    __shared__ float ssum[4];
    int b = blockIdx.x, tid = threadIdx.x;
    int lane = tid & 63, wv = tid >> 6;

    // first index where mask==0, else S  (thread tid owns s=tid, S_==256)
    int first = (masks[tid * B_ + b] == 0) ? tid : S_;
    for (int off = 32; off; off >>= 1) first = min(first, __shfl_down(first, off, 64));
    if (lane == 0) smin_s[wv] = first;

    float sum = 0.f;
    for (int i = tid; i < H_; i += 256) sum += w_proj[i] * tanhf(dwpos[(size_t)b * H_ + i]);
    for (int off = 32; off; off >>= 1) sum += __shfl_down(sum, off, 64);
    if (lane == 0) ssum[wv] = sum;
    __syncthreads();
    if (tid == 0) {
        int   fz  = min(min(smin_s[0], smin_s[1]), min(smin_s[2], smin_s[3]));
        float tot = ssum[0] + ssum[1] + ssum[2] + ssum[3];
        float fht = 1.f / (1.f + expf(-tot));
        pt[b] = ((float)fz - 1.f) * fht;
    }
}

// ---------------------------------------------------------------- energy[s,b] = masked tanh(dw[b].enc[s,b])
__global__ __launch_bounds__(256) void energy_kernel(const float* __restrict__ dw,
                                                     const float* __restrict__ enc,
                                                     const int* __restrict__ masks,
                                                     float* __restrict__ energy)
{
    int wid  = (blockIdx.x << 2) + (threadIdx.x >> 6);  // wid = s*B + b
    int lane = threadIdx.x & 63;
    int b    = wid & (B_ - 1);
    const float4* ep = (const float4*)(enc + (size_t)wid * H_);
    const float4* dp = (const float4*)(dw + (size_t)b * H_);
    float acc = 0.f;
    #pragma unroll
    for (int i = 0; i < 4; i++) {                       // H/4/64 = 4
        float4 a = dp[lane + (i << 6)];
        float4 e = ep[lane + (i << 6)];
        acc += a.x * e.x + a.y * e.y + a.z * e.z + a.w * e.w;
    }
    for (int off = 32; off; off >>= 1) acc += __shfl_down(acc, off, 64);
    if (lane == 0)
        energy[wid] = masks[wid] ? tanhf(acc) : -1e30f;
}

// ---------------------------------------------------------------- softmax over S (per b) * local window
__global__ __launch_bounds__(256) void softmax_window(const float* __restrict__ energy,
                                                      const float* __restrict__ pt,
                                                      float* __restrict__ w_sb)
{
    __shared__ float sred[4];
    int b = blockIdx.x, s = threadIdx.x;   // S_==256
    int lane = s & 63, wv = s >> 6;
    float e = energy[s * B_ + b];

    float m = e;
    for (int off = 32; off; off >>= 1) m = fmaxf(m, __shfl_down(m, off, 64));
    if (lane == 0) sred[wv] = m;
    __syncthreads();
    m = fmaxf(fmaxf(sred[0], sred[1]), fmaxf(sred[2], sred[3]));
    __syncthreads();

    float ex = expf(e - m);
    float l = ex;
    for (int off = 32; off; off >>= 1) l += __shfl_down(l, off, 64);
    if (lane == 0) sred[wv] = l;
    __syncthreads();
    l = sred[0] + sred[1] + sred[2] + sred[3];

    float aw   = ex / l;
    float ptb  = pt[b];
    float fs   = (float)s;
    float pmax = floorf(ptb + 5.f);
    float pmin = floorf(fmaxf(ptb - 5.f, 0.f));
    float d    = ptb - fs;
    float win  = ((fs < pmax) && (fs >= pmin)) ? expf(-(d * d) * (1.f / 12.5f)) : 0.f;
    w_sb[s * B_ + b] = aw * win;
}

// ---------------------------------------------------------------- context[b,h] = sum_s w[s,b]*enc[s,b,h] (sparse window)
__global__ __launch_bounds__(256) void context_kernel(const float* __restrict__ w_sb,
                                                      const float* __restrict__ enc,
                                                      const float* __restrict__ pt,
                                                      float* __restrict__ ctx)
{
    int b = blockIdx.y;
    int h = blockIdx.x * 256 + threadIdx.x;
    float ptb = pt[b];
    int smin = (int)floorf(fmaxf(ptb - 5.f, 0.f));
    int smax = min((int)floorf(ptb + 5.f), S_);
    float acc = 0.f;
    for (int s = smin; s < smax; s++)
        acc += w_sb[s * B_ + b] * enc[(size_t)(s * B_ + b) * H_ + h];
    ctx[(size_t)b * H_ + h] = acc;
}

// ---------------------------------------------------------------- concats
__global__ __launch_bounds__(256) void concat_gru_in(const float* __restrict__ x_emb,
                                                     const float* __restrict__ ctx,
                                                     float* __restrict__ gru_in)
{
    int idx = blockIdx.x * 256 + threadIdx.x;   // B*(E+H)
    int b = idx / (E_ + H_);
    int k = idx - b * (E_ + H_);
    gru_in[idx] = (k < E_) ? x_emb[b * E_ + k] : ctx[(size_t)b * H_ + k - E_];
}

__global__ __launch_bounds__(256) void concat_new_input(const float* __restrict__ x_emb,
                                                        const float* __restrict__ h_new,
                                                        const float* __restrict__ ctx,
                                                        float* __restrict__ ni)
{
    int idx = blockIdx.x * 256 + threadIdx.x;   // B*(E+2H)
    int b = idx / (E_ + 2 * H_);
    int k = idx - b * (E_ + 2 * H_);
    float v;
    if (k < E_)            v = x_emb[b * E_ + k];
    else if (k < E_ + H_)  v = h_new[(size_t)b * H_ + k - E_];
    else                   v = ctx[(size_t)b * H_ + k - E_ - H_];
    ni[idx] = v;
}

// ---------------------------------------------------------------- GRU epilogue
__global__ __launch_bounds__(256) void gru_kernel(const float* __restrict__ gi,
                                                  const float* __restrict__ gh,
                                                  const float* __restrict__ phd,
                                                  float* __restrict__ h_new,
                                                  float* __restrict__ out_h)
{
    int idx = blockIdx.x * 256 + threadIdx.x;   // B*H
    int b = idx >> 10;
    int i = idx & 1023;
    const float* gib = gi + (size_t)b * 3 * H_;
    const float* ghb = gh + (size_t)b * 3 * H_;
    float ir = gib[i], iz = gib[H_ + i], in_ = gib[2 * H_ + i];
    float hr = ghb[i], hz = ghb[H_ + i], hn  = ghb[2 * H_ + i];
    float r  = 1.f / (1.f + expf(-(ir + hr)));
    float zg = 1.f / (1.f + expf(-(iz + hz)));
    float n  = tanhf(in_ + r * hn);
    float h  = (1.f - zg) * n + zg * phd[idx];
    h_new[idx] = h;
    out_h[idx] = h;
}

// ---------------------------------------------------------------- launch
extern "C" void kernel_launch(void* const* d_in, const int* in_sizes, int n_in,
                              void* d_out, int out_size, void* d_ws, size_t ws_size,
                              hipStream_t stream)
{
    const int*   x      = (const int*)  d_in[0];
    const float* phd    = (const float*)d_in[1];   // (1,B,H) == B x H
    const float* enc    = (const float*)d_in[2];   // (S,B,H)
    const int*   masks  = (const int*)  d_in[3];   // (S,B)
    const float* emb    = (const float*)d_in[4];
    const float* W_dec  = (const float*)d_in[5];
    const float* b_dec  = (const float*)d_in[6];
    const float* W_pos  = (const float*)d_in[7];
    const float* b_pos  = (const float*)d_in[8];
    const float* w_proj = (const float*)d_in[9];
    const float* W_ih   = (const float*)d_in[10];
    const float* b_ih   = (const float*)d_in[11];
    const float* W_hh   = (const float*)d_in[12];
    const float* b_hh   = (const float*)d_in[13];
    const float* W_fc   = (const float*)d_in[14];
    const float* b_fc   = (const float*)d_in[15];

    float* out_z = (float*)d_out;                   // (1,B,V)
    float* out_h = out_z + (size_t)B_ * V_;         // (1,B,H)

    float* ws       = (float*)d_ws;
    float* x_emb    = ws;  ws += B_ * E_;
    float* dwdec    = ws;  ws += B_ * H_;
    float* dwpos    = ws;  ws += B_ * H_;
    float* pt       = ws;  ws += 128;
    float* energy   = ws;  ws += S_ * B_;
    float* w_sb     = ws;  ws += S_ * B_;
    float* ctx      = ws;  ws += B_ * H_;
    float* gru_in   = ws;  ws += B_ * (E_ + H_);
    float* gi       = ws;  ws += B_ * 3 * H_;
    float* gh       = ws;  ws += B_ * 3 * H_;
    float* h_new    = ws;  ws += B_ * H_;
    float* n_in_buf = ws;  ws += B_ * (E_ + 2 * H_);

    embed_kernel<<<B_ * E_ / 256, 256, 0, stream>>>(x, emb, x_emb);

    bias_init<<<B_ * H_ / 256, 256, 0, stream>>>(dwdec, b_dec, H_);
    bias_init<<<B_ * H_ / 256, 256, 0, stream>>>(dwpos, b_pos, H_);
    // dw = phd @ W_dec.T ; dwpos = phd @ W_pos.T    (split-K=4, fused pair)
    gemm_dual<<<dim3(H_ / 32, 4, 2), 256, 0, stream>>>(phd, W_dec, dwdec, H_, 256,
                                                       phd, W_pos, dwpos, H_, 256, H_);

    pt_kernel<<<B_, 256, 0, stream>>>(masks, dwpos, w_proj, pt);
    energy_kernel<<<S_ * B_ / 4, 256, 0, stream>>>(dwdec, enc, masks, energy);
    softmax_window<<<B_, 256, 0, stream>>>(energy, pt, w_sb);
    context_kernel<<<dim3(H_ / 256, B_), 256, 0, stream>>>(w_sb, enc, pt, ctx);

    concat_gru_in<<<B_ * (E_ + H_) / 256, 256, 0, stream>>>(x_emb, ctx, gru_in);
    bias_init<<<B_ * 3 * H_ / 256, 256, 0, stream>>>(gi, b_ih, 3 * H_);
    bias_init<<<B_ * 3 * H_ / 256, 256, 0, stream>>>(gh, b_hh, 3 * H_);
    // gi = gru_in @ W_ih.T ; gh = phd @ W_hh.T     (split-K=4, fused pair)
    gemm_dual<<<dim3(3 * H_ / 32, 4, 2), 256, 0, stream>>>(gru_in, W_ih, gi, E_ + H_, 384,
                                                           phd,    W_hh, gh, H_,      256, 3 * H_);

    gru_kernel<<<B_ * H_ / 256, 256, 0, stream>>>(gi, gh, phd, h_new, out_h);
    concat_new_input<<<B_ * (E_ + 2 * H_) / 256, 256, 0, stream>>>(x_emb, h_new, ctx, n_in_buf);

    // z = new_input @ W_fc.T + b_fc  -> out_z  (500 blocks)
    gemm_z<<<dim3(V_ / 64, 1, 1), 256, 0, stream>>>(n_in_buf, W_fc, b_fc, out_z, V_, E_ + 2 * H_);
}

// Round 2
// 706.664 us; speedup vs baseline: 1.2745x; 1.2745x over previous
//
#include <hip/hip_runtime.h>
#include <math.h>

#define B_ 128
#define S_ 256
#define H_ 1024
#define E_ 512
#define V_ 32000
#define KZ (E_ + 2 * H_)   // 2560

typedef short s8v  __attribute__((ext_vector_type(8)));
typedef float f32x4 __attribute__((ext_vector_type(4)));
typedef unsigned short us4 __attribute__((ext_vector_type(4)));
typedef unsigned short us8 __attribute__((ext_vector_type(8)));

// f32 -> bf16 round-to-nearest-even (bit trick, matches hardware RNE)
__device__ __forceinline__ unsigned short f2bf(float f)
{
    union { float f; unsigned u; } v; v.f = f;
    unsigned r = v.u + 0x7fffu + ((v.u >> 16) & 1u);
    return (unsigned short)(r >> 16);
}

// ---------------------------------------------------------------- embed gather
__global__ __launch_bounds__(256) void embed_kernel(const int* __restrict__ x,
                                                    const float* __restrict__ emb,
                                                    float* __restrict__ x_emb)
{
    int idx = blockIdx.x * 256 + threadIdx.x;     // B*E
    int b = idx >> 9;                              // E_=512
    int e = idx & 511;
    x_emb[idx] = emb[(size_t)x[b] * E_ + e];
}

// ---------------------------------------------------------------- C[b,n] = bias[n]
__global__ __launch_bounds__(256) void bias_init(float* __restrict__ C,
                                                 const float* __restrict__ bias, int N)
{
    int idx = blockIdx.x * 256 + threadIdx.x;
    int n = idx % N;
    C[idx] = bias[n];
}

// ---------------------------------------------------------------- generic f32 GEMM core (mid GEMMs)
// C[m,n] (+)= sum_k A[m,k] * W[n,k]    M=128 fixed, 256 threads, TILE_K=16
template<int TILE_N, int MICRO_N, bool ATOMIC>
__device__ __forceinline__ void gemm_core(const float* __restrict__ A,
                                          const float* __restrict__ W,
                                          const float* __restrict__ bias,
                                          float* __restrict__ C,
                                          int N, int K, int kbeg, int kend,
                                          float (*As)[132], float (*Ws)[TILE_N + 4])
{
    constexpr int NT_N   = TILE_N / MICRO_N;   // threads along n
    constexpr int NT_M   = 256 / NT_N;         // threads along m
    constexpr int MICRO_M = 128 / NT_M;        // rows per thread
    const int tid = threadIdx.x;
    const int n0  = blockIdx.x * TILE_N;
    const int tn  = (tid % NT_N) * MICRO_N;
    const int tm  = (tid / NT_N) * MICRO_M;

    float acc[MICRO_M][MICRO_N] = {};

    for (int k0 = kbeg; k0 < kend; k0 += 16) {
        #pragma unroll
        for (int r = 0; r < 2; r++) {
            int v  = tid + 256 * r;
            int m  = v >> 2;
            int kk = (v & 3) << 2;
            float4 a4 = *(const float4*)(A + (size_t)m * K + k0 + kk);
            As[kk + 0][m] = a4.x; As[kk + 1][m] = a4.y;
            As[kk + 2][m] = a4.z; As[kk + 3][m] = a4.w;
        }
        for (int v = tid; v < TILE_N * 4; v += 256) {
            int n  = v >> 2;
            int kk = (v & 3) << 2;
            float4 w4 = *(const float4*)(W + (size_t)(n0 + n) * K + k0 + kk);
            Ws[kk + 0][n] = w4.x; Ws[kk + 1][n] = w4.y;
            Ws[kk + 2][n] = w4.z; Ws[kk + 3][n] = w4.w;
        }
        __syncthreads();
        #pragma unroll
        for (int kk = 0; kk < 16; kk++) {
            float a[MICRO_M], w[MICRO_N];
            #pragma unroll
            for (int i = 0; i < MICRO_M; i++) a[i] = As[kk][tm + i];
            #pragma unroll
            for (int j = 0; j < MICRO_N; j++) w[j] = Ws[kk][tn + j];
            #pragma unroll
            for (int i = 0; i < MICRO_M; i++)
                #pragma unroll
                for (int j = 0; j < MICRO_N; j++)
                    acc[i][j] = fmaf(a[i], w[j], acc[i][j]);
        }
        __syncthreads();
    }

    #pragma unroll
    for (int i = 0; i < MICRO_M; i++) {
        #pragma unroll
        for (int j = 0; j < MICRO_N; j++) {
            size_t off = (size_t)(tm + i) * N + n0 + tn + j;
            if (ATOMIC) atomicAdd(C + off, acc[i][j]);
            else        C[off] = acc[i][j] + bias[n0 + tn + j];
        }
    }
}

// dual mid GEMM: two problems selected by blockIdx.z, split-K via blockIdx.y,
// atomicAdd into bias-pre-initialized C
__global__ __launch_bounds__(256) void gemm_dual(const float* A0, const float* W0, float* C0, int K0, int kc0,
                                                 const float* A1, const float* W1, float* C1, int K1, int kc1,
                                                 int N)
{
    __shared__ float As[16][132];
    __shared__ float Ws[16][36];
    if (blockIdx.z == 0)
        gemm_core<32, 2, true>(A0, W0, nullptr, C0, N, K0,
                               blockIdx.y * kc0, blockIdx.y * kc0 + kc0, As, Ws);
    else
        gemm_core<32, 2, true>(A1, W1, nullptr, C1, N, K1,
                               blockIdx.y * kc1, blockIdx.y * kc1 + kc1, As, Ws);
}

// ---------------------------------------------------------------- MFMA big GEMM (z)
// C[m,n] = sum_k A[m,k]*W[n,k] + bias[n]; A is bf16 (pre-converted),
// W is f32 converted to bf16 during staging. M=128, BN=64, BK=32.
// 4 waves: wave w covers n in [w*16, w*16+16), full M=128 (8 MFMA tiles).
__global__ __launch_bounds__(256) void gemm_z_mfma(const unsigned short* __restrict__ A,
                                                   const float* __restrict__ W,
                                                   const float* __restrict__ bias,
                                                   float* __restrict__ C)
{
    __shared__ unsigned short As[128 * 40];   // row stride 40 bf16 (80 B, 20 banks)
    __shared__ unsigned short Ws[64 * 40];

    const int tid  = threadIdx.x;
    const int n0   = blockIdx.x * 64;
    const int w    = tid >> 6;
    const int lane = tid & 63;
    const int quad = lane >> 4;
    const int l16  = lane & 15;

    f32x4 acc[8] = {};

    for (int k0 = 0; k0 < KZ; k0 += 32) {
        // ---- stage A: 128x32 bf16 = 512 x (8 bf16), 2 per thread
        #pragma unroll
        for (int r = 0; r < 2; r++) {
            int idx = tid + 256 * r;
            int m   = idx >> 2;
            int kk  = (idx & 3) << 3;
            *(us8*)&As[m * 40 + kk] = *(const us8*)(A + (size_t)m * KZ + k0 + kk);
        }
        // ---- stage W: 64x32 f32 -> bf16, 512 x float4, 2 per thread
        #pragma unroll
        for (int r = 0; r < 2; r++) {
            int idx = tid + 256 * r;
            int n   = idx >> 3;
            int kk  = (idx & 7) << 2;
            float4 wv = *(const float4*)(W + (size_t)(n0 + n) * KZ + k0 + kk);
            us4 p; p.x = f2bf(wv.x); p.y = f2bf(wv.y); p.z = f2bf(wv.z); p.w = f2bf(wv.w);
            *(us4*)&Ws[n * 40 + kk] = p;
        }
        __syncthreads();

        s8v bfrag = *(const s8v*)&Ws[(w * 16 + l16) * 40 + quad * 8];
        #pragma unroll
        for (int mt = 0; mt < 8; mt++) {
            s8v afrag = *(const s8v*)&As[(mt * 16 + l16) * 40 + quad * 8];
            acc[mt] = __builtin_amdgcn_mfma_f32_16x16x32_bf16(afrag, bfrag, acc[mt], 0, 0, 0);
        }
        __syncthreads();
    }

    const int n  = n0 + w * 16 + l16;
    const float bv = bias[n];
    #pragma unroll
    for (int mt = 0; mt < 8; mt++) {
        #pragma unroll
        for (int r = 0; r < 4; r++) {
            int m = mt * 16 + quad * 4 + r;
            C[(size_t)m * V_ + n] = acc[mt][r] + bv;
        }
    }
}

// ---------------------------------------------------------------- pt = (len-1)*sigmoid(w_proj . tanh(dwpos))
__global__ __launch_bounds__(256) void pt_kernel(const int* __restrict__ masks,
                                                 const float* __restrict__ dwpos,
                                                 const float* __restrict__ w_proj,
                                                 float* __restrict__ pt)
{
    __shared__ int   smin_s[4];
    __shared__ float ssum[4];
    int b = blockIdx.x, tid = threadIdx.x;
    int lane = tid & 63, wv = tid >> 6;

    int first = (masks[tid * B_ + b] == 0) ? tid : S_;
    for (int off = 32; off; off >>= 1) first = min(first, __shfl_down(first, off, 64));
    if (lane == 0) smin_s[wv] = first;

    float sum = 0.f;
    for (int i = tid; i < H_; i += 256) sum += w_proj[i] * tanhf(dwpos[(size_t)b * H_ + i]);
    for (int off = 32; off; off >>= 1) sum += __shfl_down(sum, off, 64);
    if (lane == 0) ssum[wv] = sum;
    __syncthreads();
    if (tid == 0) {
        int   fz  = min(min(smin_s[0], smin_s[1]), min(smin_s[2], smin_s[3]));
        float tot = ssum[0] + ssum[1] + ssum[2] + ssum[3];
        float fht = 1.f / (1.f + expf(-tot));
        pt[b] = ((float)fz - 1.f) * fht;
    }
}

// ---------------------------------------------------------------- energy[s,b] = masked tanh(dw[b].enc[s,b])
__global__ __launch_bounds__(256) void energy_kernel(const float* __restrict__ dw,
                                                     const float* __restrict__ enc,
                                                     const int* __restrict__ masks,
                                                     float* __restrict__ energy)
{
    int wid  = (blockIdx.x << 2) + (threadIdx.x >> 6);  // wid = s*B + b
    int lane = threadIdx.x & 63;
    int b    = wid & (B_ - 1);
    const float4* ep = (const float4*)(enc + (size_t)wid * H_);
    const float4* dp = (const float4*)(dw + (size_t)b * H_);
    float acc = 0.f;
    #pragma unroll
    for (int i = 0; i < 4; i++) {
        float4 a = dp[lane + (i << 6)];
        float4 e = ep[lane + (i << 6)];
        acc += a.x * e.x + a.y * e.y + a.z * e.z + a.w * e.w;
    }
    for (int off = 32; off; off >>= 1) acc += __shfl_down(acc, off, 64);
    if (lane == 0)
        energy[wid] = masks[wid] ? tanhf(acc) : -1e30f;
}

// ---------------------------------------------------------------- softmax over S (per b) * local window
__global__ __launch_bounds__(256) void softmax_window(const float* __restrict__ energy,
                                                      const float* __restrict__ pt,
                                                      float* __restrict__ w_sb)
{
    __shared__ float sred[4];
    int b = blockIdx.x, s = threadIdx.x;
    int lane = s & 63, wv = s >> 6;
    float e = energy[s * B_ + b];

    float m = e;
    for (int off = 32; off; off >>= 1) m = fmaxf(m, __shfl_down(m, off, 64));
    if (lane == 0) sred[wv] = m;
    __syncthreads();
    m = fmaxf(fmaxf(sred[0], sred[1]), fmaxf(sred[2], sred[3]));
    __syncthreads();

    float ex = expf(e - m);
    float l = ex;
    for (int off = 32; off; off >>= 1) l += __shfl_down(l, off, 64);
    if (lane == 0) sred[wv] = l;
    __syncthreads();
    l = sred[0] + sred[1] + sred[2] + sred[3];

    float aw   = ex / l;
    float ptb  = pt[b];
    float fs   = (float)s;
    float pmax = floorf(ptb + 5.f);
    float pmin = floorf(fmaxf(ptb - 5.f, 0.f));
    float d    = ptb - fs;
    float win  = ((fs < pmax) && (fs >= pmin)) ? expf(-(d * d) * (1.f / 12.5f)) : 0.f;
    w_sb[s * B_ + b] = aw * win;
}

// ---------------------------------------------------------------- context[b,h] = sum_s w[s,b]*enc[s,b,h] (sparse window)
__global__ __launch_bounds__(256) void context_kernel(const float* __restrict__ w_sb,
                                                      const float* __restrict__ enc,
                                                      const float* __restrict__ pt,
                                                      float* __restrict__ ctx)
{
    int b = blockIdx.y;
    int h = blockIdx.x * 256 + threadIdx.x;
    float ptb = pt[b];
    int smin = (int)floorf(fmaxf(ptb - 5.f, 0.f));
    int smax = min((int)floorf(ptb + 5.f), S_);
    float acc = 0.f;
    for (int s = smin; s < smax; s++)
        acc += w_sb[s * B_ + b] * enc[(size_t)(s * B_ + b) * H_ + h];
    ctx[(size_t)b * H_ + h] = acc;
}

// ---------------------------------------------------------------- concats
__global__ __launch_bounds__(256) void concat_gru_in(const float* __restrict__ x_emb,
                                                     const float* __restrict__ ctx,
                                                     float* __restrict__ gru_in)
{
    int idx = blockIdx.x * 256 + threadIdx.x;   // B*(E+H)
    int b = idx / (E_ + H_);
    int k = idx - b * (E_ + H_);
    gru_in[idx] = (k < E_) ? x_emb[b * E_ + k] : ctx[(size_t)b * H_ + k - E_];
}

// new_input emitted as bf16 (A operand of gemm_z_mfma)
__global__ __launch_bounds__(256) void concat_new_input(const float* __restrict__ x_emb,
                                                        const float* __restrict__ h_new,
                                                        const float* __restrict__ ctx,
                                                        unsigned short* __restrict__ ni)
{
    int idx = blockIdx.x * 256 + threadIdx.x;   // B*(E+2H)
    int b = idx / (E_ + 2 * H_);
    int k = idx - b * (E_ + 2 * H_);
    float v;
    if (k < E_)            v = x_emb[b * E_ + k];
    else if (k < E_ + H_)  v = h_new[(size_t)b * H_ + k - E_];
    else                   v = ctx[(size_t)b * H_ + k - E_ - H_];
    ni[idx] = f2bf(v);
}

// ---------------------------------------------------------------- GRU epilogue
__global__ __launch_bounds__(256) void gru_kernel(const float* __restrict__ gi,
                                                  const float* __restrict__ gh,
                                                  const float* __restrict__ phd,
                                                  float* __restrict__ h_new,
                                                  float* __restrict__ out_h)
{
    int idx = blockIdx.x * 256 + threadIdx.x;   // B*H
    int b = idx >> 10;
    int i = idx & 1023;
    const float* gib = gi + (size_t)b * 3 * H_;
    const float* ghb = gh + (size_t)b * 3 * H_;
    float ir = gib[i], iz = gib[H_ + i], in_ = gib[2 * H_ + i];
    float hr = ghb[i], hz = ghb[H_ + i], hn  = ghb[2 * H_ + i];
    float r  = 1.f / (1.f + expf(-(ir + hr)));
    float zg = 1.f / (1.f + expf(-(iz + hz)));
    float n  = tanhf(in_ + r * hn);
    float h  = (1.f - zg) * n + zg * phd[idx];
    h_new[idx] = h;
    out_h[idx] = h;
}

// ---------------------------------------------------------------- launch
extern "C" void kernel_launch(void* const* d_in, const int* in_sizes, int n_in,
                              void* d_out, int out_size, void* d_ws, size_t ws_size,
                              hipStream_t stream)
{
    const int*   x      = (const int*)  d_in[0];
    const float* phd    = (const float*)d_in[1];   // (1,B,H)
    const float* enc    = (const float*)d_in[2];   // (S,B,H)
    const int*   masks  = (const int*)  d_in[3];   // (S,B)
    const float* emb    = (const float*)d_in[4];
    const float* W_dec  = (const float*)d_in[5];
    const float* b_dec  = (const float*)d_in[6];
    const float* W_pos  = (const float*)d_in[7];
    const float* b_pos  = (const float*)d_in[8];
    const float* w_proj = (const float*)d_in[9];
    const float* W_ih   = (const float*)d_in[10];
    const float* b_ih   = (const float*)d_in[11];
    const float* W_hh   = (const float*)d_in[12];
    const float* b_hh   = (const float*)d_in[13];
    const float* W_fc   = (const float*)d_in[14];
    const float* b_fc   = (const float*)d_in[15];

    float* out_z = (float*)d_out;                   // (1,B,V)
    float* out_h = out_z + (size_t)B_ * V_;         // (1,B,H)

    float* ws       = (float*)d_ws;
    float* x_emb    = ws;  ws += B_ * E_;
    float* dwdec    = ws;  ws += B_ * H_;
    float* dwpos    = ws;  ws += B_ * H_;
    float* pt       = ws;  ws += 128;
    float* energy   = ws;  ws += S_ * B_;
    float* w_sb     = ws;  ws += S_ * B_;
    float* ctx      = ws;  ws += B_ * H_;
    float* gru_in   = ws;  ws += B_ * (E_ + H_);
    float* gi       = ws;  ws += B_ * 3 * H_;
    float* gh       = ws;  ws += B_ * 3 * H_;
    float* h_new    = ws;  ws += B_ * H_;
    unsigned short* n_in_bf = (unsigned short*)ws;  // B*(E+2H) bf16

    embed_kernel<<<B_ * E_ / 256, 256, 0, stream>>>(x, emb, x_emb);

    bias_init<<<B_ * H_ / 256, 256, 0, stream>>>(dwdec, b_dec, H_);
    bias_init<<<B_ * H_ / 256, 256, 0, stream>>>(dwpos, b_pos, H_);
    gemm_dual<<<dim3(H_ / 32, 4, 2), 256, 0, stream>>>(phd, W_dec, dwdec, H_, 256,
                                                       phd, W_pos, dwpos, H_, 256, H_);

    pt_kernel<<<B_, 256, 0, stream>>>(masks, dwpos, w_proj, pt);
    energy_kernel<<<S_ * B_ / 4, 256, 0, stream>>>(dwdec, enc, masks, energy);
    softmax_window<<<B_, 256, 0, stream>>>(energy, pt, w_sb);
    context_kernel<<<dim3(H_ / 256, B_), 256, 0, stream>>>(w_sb, enc, pt, ctx);

    concat_gru_in<<<B_ * (E_ + H_) / 256, 256, 0, stream>>>(x_emb, ctx, gru_in);
    bias_init<<<B_ * 3 * H_ / 256, 256, 0, stream>>>(gi, b_ih, 3 * H_);
    bias_init<<<B_ * 3 * H_ / 256, 256, 0, stream>>>(gh, b_hh, 3 * H_);
    gemm_dual<<<dim3(3 * H_ / 32, 4, 2), 256, 0, stream>>>(gru_in, W_ih, gi, E_ + H_, 384,
                                                           phd,    W_hh, gh, H_,      256, 3 * H_);

    gru_kernel<<<B_ * H_ / 256, 256, 0, stream>>>(gi, gh, phd, h_new, out_h);
    concat_new_input<<<B_ * (E_ + 2 * H_) / 256, 256, 0, stream>>>(x_emb, h_new, ctx, n_in_bf);

    // z = new_input @ W_fc.T + b_fc  (bf16 MFMA, 500 blocks)
    gemm_z_mfma<<<V_ / 64, 256, 0, stream>>>(n_in_bf, W_fc, b_fc, out_z);
}